// Round 7
// baseline (207.321 us; speedup 1.0000x reference)
//
#include <hip/hip_runtime.h>
#include <cstddef>

// SpatialConv KERNEL_TYPE=0: 5-tap plus conv, N=16 Ci=Co=256 H=W=64, fp32 I/O.
// bf16 MFMA (32x32x16). xb bf16 prepass; conv stages x via global_load_lds DMA
// (no register consumer -> compiler cannot force an early vmcnt drain).
// K-loop: ONE __syncthreads per chunk; prefetch DMA for chunk c+1 is issued
// AFTER the barrier of chunk c and drained by the barrier of chunk c+1, so it
// flies under the whole MFMA phase. A-loads issue before the DMAs (FIFO: their
// consumption leaves the DMAs in flight). 3 blocks/CU de-phase the barriers.
#define N_  16
#define CI  256
#define CO  256
#define KT  5

typedef __attribute__((ext_vector_type(8)))  short  short8;
typedef __attribute__((ext_vector_type(8)))  unsigned short ushort8;
typedef __attribute__((ext_vector_type(16))) float  floatx16;

typedef const __attribute__((address_space(1))) unsigned int gas_uint;
typedef __attribute__((address_space(3))) unsigned int las_uint;

static __device__ __forceinline__ unsigned short f2bf(float f) {
    union { float f; unsigned u; } v; v.f = f;
    unsigned r = v.u + 0x7fff + ((v.u >> 16) & 1);   // RNE
    return (unsigned short)(r >> 16);
}

// ---- prepass 1: w fp32 [Co][Ci][5] -> wb bf16 [5][Co][Ci] (c contiguous) ----
__global__ void wtrans_kernel(const float* __restrict__ w, unsigned short* __restrict__ wb) {
    int idx = blockIdx.x * 256 + threadIdx.x;
    if (idx >= KT * CO * CI) return;
    int k = idx >> 16;
    int rem = idx & 65535;
    int o = rem >> 8;
    int c = rem & 255;
    wb[idx] = f2bf(w[(size_t)o * (CI * KT) + c * KT + k]);
}

// ---- prepass 2: x fp32 NCHW -> xb bf16 [N][c/8][H][W][8c]. No LDS/barriers.
__global__ __launch_bounds__(256) void xtrans_kernel(const float* __restrict__ x,
                                                     unsigned short* __restrict__ xb) {
    int idx = blockIdx.x * 256 + threadIdx.x;       // over 16*32*64*64 = 2097152
    int w  = idx & 63;
    int h  = (idx >> 6) & 63;
    int cg = (idx >> 12) & 31;
    int n  = idx >> 17;
    const float* xp = x + (((size_t)n * CI + cg * 8) * 64 + h) * 64 + w;
    ushort8 v;
    #pragma unroll
    for (int e = 0; e < 8; ++e) v[e] = f2bf(xp[(size_t)e * 4096]);
    *(ushort8*)(xb + (size_t)idx * 8) = v;
}

// ---- main: block = 128 o x (2 h-rows x 64 w); 4 waves = (osub, row); ----
// wave = 64 o x 64 px -> acc[2 ot][2 wt] floatx16 = 64 VGPRs.
// LDS cell(r, part, w) = 16B of 8 bf16 c; slot = r*256 + part*64 + w.
//   r = 0..3 -> image row h0-1..h0+2 ; part = c-group-of-8 in chunk ; w = col.
__global__ __launch_bounds__(256, 3) void conv_mfma(const unsigned short* __restrict__ xb,
                                                    const unsigned short* __restrict__ wb,
                                                    float* __restrict__ out) {
    __shared__ ushort8 lds[2 * 1024 + 1];   // 2 x 16 KB + zero cell

    const int tid  = threadIdx.x;
    const int bx   = blockIdx.x;
    const int oh   = bx & 1;
    const int hp   = (bx >> 1) & 31;
    const int n    = bx >> 6;
    const int h0   = hp * 2;
    const int lane = tid & 63;
    const int wv   = tid >> 6;
    const int l31  = lane & 31;
    const int lh   = lane >> 5;
    const int osub = wv & 1;
    const int row  = wv >> 1;                 // wave's h-row: h = h0 + row
    const int obase0 = oh * 128 + osub * 64;  // wave o-base (2 tiles of 32)

    // staging map: thread -> (part = wv, w = lane); 4 rows via loop.
    const int sw = tid & 63;
    const int spart = tid >> 6;

    // pre-zero: zero cell + never-staged edge rows (both buffers)
    if (tid == 0) lds[2048] = (ushort8)0;
    if (hp == 0)  { lds[0 * 1024 + tid] = (ushort8)0; lds[1 * 1024 + tid] = (ushort8)0; }
    if (hp == 31) { lds[0 * 1024 + 768 + tid] = (ushort8)0; lds[1 * 1024 + 768 + tid] = (ushort8)0; }

    auto stage = [&](int c, int b) {
        #pragma unroll
        for (int r = 0; r < 4; ++r) {
            const int hh = h0 + r - 1;                     // block-uniform validity
            if ((unsigned)hh < 64u) {
                const unsigned short* g =
                    xb + (((size_t)(n * 32 + c * 4 + spart) * 64 + hh) * 64 + sw) * 8;
                __builtin_amdgcn_global_load_lds(
                    (gas_uint*)g,
                    (las_uint*)&lds[b * 1024 + r * 256 + spart * 64 + sw],
                    16, 0, 0);
            }
        }
    };

    floatx16 acc[2][2];   // [ot][wt]
    #pragma unroll
    for (int ot = 0; ot < 2; ++ot)
        #pragma unroll
        for (int wt = 0; wt < 2; ++wt)
            #pragma unroll
            for (int e = 0; e < 16; ++e) acc[ot][wt][e] = 0.f;

    const char* zcell = (const char*)&lds[2048];
    const int laneoff = l31 * 16;

    // one tap's 8 MFMAs: taps (dy,dx): k0(1,1) k1(0,1) k2(1,0) k3(1,2) k4(2,1)
    auto mfma_tap = [&](const char* bufb, const short8 a[2][2], int k) {
        const int dy = (k == 1) ? 0 : (k == 4) ? 2 : 1;
        const int dx = (k == 2) ? 0 : (k == 3) ? 2 : 1;
        const int r  = row + dy;                           // 0..3
        #pragma unroll
        for (int ks = 0; ks < 2; ++ks) {
            #pragma unroll
            for (int wt = 0; wt < 2; ++wt) {
                const int wlb = wt * 32 + dx - 1;          // lane wl = wlb + l31
                const int wl  = wlb + l31;
                const char* bp = ((unsigned)wl < 64u)
                    ? bufb + (r * 4096 + (ks * 2 + lh) * 1024 + wlb * 16) + laneoff
                    : zcell;
                const short8 bfrag = *(const short8*)bp;
                acc[0][wt] = __builtin_amdgcn_mfma_f32_32x32x16_bf16(a[ks][0], bfrag, acc[0][wt], 0, 0, 0);
                acc[1][wt] = __builtin_amdgcn_mfma_f32_32x32x16_bf16(a[ks][1], bfrag, acc[1][wt], 0, 0, 0);
            }
        }
    };

    stage(0, 0);

    for (int c = 0; c < 8; ++c) {
        const int cb = c & 1;
        // Drains vmcnt(0)+lgkmcnt(0): chunk-c DMAs landed; all waves finished
        // reading buffer cb^1 (their chunk c-1 reads precede this barrier).
        __syncthreads();

        const unsigned short* wbase = wb + (size_t)(obase0 + l31) * 256 + c * 32 + lh * 8;

        // A-group taps 0-1 (8 x 16B) BEFORE the prefetch DMAs (FIFO-safe)
        short8 a01[2][2][2];   // [k][ks][ot]
        #pragma unroll
        for (int k = 0; k < 2; ++k)
            #pragma unroll
            for (int ks = 0; ks < 2; ++ks)
                #pragma unroll
                for (int ot = 0; ot < 2; ++ot)
                    a01[k][ks][ot] = *(const short8*)(wbase + (size_t)k * 65536 + ot * 8192 + ks * 16);

        // prefetch chunk c+1: in flight under the whole MFMA phase, drained by
        // the NEXT __syncthreads. No register consumer -> no early drain.
        if (c < 7) stage(c + 1, cb ^ 1);

        const char* bufb = (const char*)&lds[cb * 1024];
        mfma_tap(bufb, a01[0], 0);
        mfma_tap(bufb, a01[1], 1);

        // A-group taps 2-3 (issued after DMAs; by their consumption the DMAs
        // have had ~16 MFMAs x all waves to land - drain is cheap)
        short8 a23[2][2][2];
        #pragma unroll
        for (int k = 2; k < 4; ++k)
            #pragma unroll
            for (int ks = 0; ks < 2; ++ks)
                #pragma unroll
                for (int ot = 0; ot < 2; ++ot)
                    a23[k - 2][ks][ot] = *(const short8*)(wbase + (size_t)k * 65536 + ot * 8192 + ks * 16);
        mfma_tap(bufb, a23[0], 2);
        mfma_tap(bufb, a23[1], 3);

        short8 a4[2][2];
        #pragma unroll
        for (int ks = 0; ks < 2; ++ks)
            #pragma unroll
            for (int ot = 0; ot < 2; ++ot)
                a4[ks][ot] = *(const short8*)(wbase + (size_t)4 * 65536 + ot * 8192 + ks * 16);
        mfma_tap(bufb, a4, 4);
    }

    // epilogue: C/D: col(px w) = l31, row(o-off) = (reg&3) + 8*(reg>>2) + 4*lh
    const int h = h0 + row;
    #pragma unroll
    for (int ot = 0; ot < 2; ++ot) {
        #pragma unroll
        for (int wt = 0; wt < 2; ++wt) {
            #pragma unroll
            for (int reg = 0; reg < 16; ++reg) {
                int o = obase0 + ot * 32 + (reg & 3) + 8 * (reg >> 2) + 4 * lh;
                out[(((size_t)n * CO + o) * 64 + h) * 64 + wt * 32 + l31] = acc[ot][wt][reg];
            }
        }
    }
}

extern "C" void kernel_launch(void* const* d_in, const int* in_sizes, int n_in,
                              void* d_out, int out_size, void* d_ws, size_t ws_size,
                              hipStream_t stream) {
    const float* x = (const float*)d_in[0];
    const float* w = (const float*)d_in[1];
    float* out = (float*)d_out;

    unsigned short* wb = (unsigned short*)d_ws;                                     // 640 KB
    unsigned short* xb = (unsigned short*)((char*)d_ws + (size_t)KT * CO * CI * 2); // 33.5 MB

    wtrans_kernel<<<dim3((KT * CO * CI + 255) / 256), dim3(256), 0, stream>>>(w, wb);
    xtrans_kernel<<<dim3(16 * 32 * 64 * 64 / 256), dim3(256), 0, stream>>>(x, xb);
    conv_mfma<<<dim3(N_ * 32 * 2), dim3(256), 0, stream>>>(xb, wb, out);
}